// Round 4
// baseline (1883.966 us; speedup 1.0000x reference)
//
#include <hip/hip_runtime.h>

#define HO 62
#define WO 62
#define CIN 32
#define COUT 64
#define NB 16
#define KR 288                 // floats per (pos,o) weight row
#define JT 2                   // j positions per block
#define NCH 8                  // chunks of 4 input channels
#define CHF 36                 // floats per row per chunk (4c * 9)
#define POSF (COUT * KR)       // 18432 floats per position
#define CHUNK_SLOTS 1152       // 16B granules per chunk (JT*64*9)
#define CHUNK_FLOATS 4608

typedef float f2 __attribute__((ext_vector_type(2)));
typedef float f4 __attribute__((ext_vector_type(4)));

__device__ __forceinline__ float sigmoidf(float v) { return 1.0f / (1.0f + __expf(-v)); }

__device__ __forceinline__ void dma16(const float* g, float* l) {
    __builtin_amdgcn_global_load_lds(
        (const __attribute__((address_space(1))) void*)g,
        (__attribute__((address_space(3))) void*)l, 16, 0, 0);
}

__global__ __launch_bounds__(256, 2)
void lc2d_kernel(const float* __restrict__ x,
                 const float* __restrict__ wgt,
                 float* __restrict__ out)
{
    // weight chunk, transposed granule layout: slot = pos*576 + k4*64 + o
    __shared__ __align__(16) float wls[2][CHUNK_FLOATS];  // 36864 B
    __shared__ __align__(16) float xls[CIN][3][4][NB];    // 24576 B

    const int blk = blockIdx.x;
    const int i  = blk % HO;
    const int j0 = (blk / HO) * JT;       // 31 tiles cover 62 exactly
    const int t  = threadIdx.x;
    const int wv = t >> 6;
    const int ln = t & 63;

    // ---- DMA descriptors: granule m = t + 256*s; slot->(pos,k4,o) ----
    int goff[5];
    #pragma unroll
    for (int s = 0; s < 5; s++) {
        int m = t + (s << 8);
        if (m >= CHUNK_SLOTS) m -= CHUNK_SLOTS;   // inactive lanes only; keep valid
        const int pos = m / 576;
        const int rem = m - pos * 576;
        const int k4  = rem >> 6;
        const int o   = rem & 63;
        goff[s] = pos * POSF + o * KR + k4 * 4;
    }
    const int nS = (wv < 2) ? 5 : 4;              // 1152 = 4*256 + 128
    const float* wslab = wgt + (size_t)(i * WO + j0) * POSF;

    // ---- x staging (once): xls[c][kh][col][b], cols j0..j0+3, j0 even -> 8B aligned ----
    #pragma unroll
    for (int s = 0; s < 6; s++) {
        const int r   = t + (s << 8);
        const int b   = r & 15;
        const int ckh = r >> 4;                   // 0..95
        const int c   = ckh / 3;
        const int kh  = ckh - c * 3;
        const float* src = x + ((size_t)(b * CIN + c) * 64 + (i + kh)) * 64 + j0;
        const f2 a0 = *(const f2*)(src);
        const f2 a1 = *(const f2*)(src + 2);
        xls[c][kh][0][b] = a0.x; xls[c][kh][1][b] = a0.y;
        xls[c][kh][2][b] = a1.x; xls[c][kh][3][b] = a1.y;
    }

    // ---- chunk 0 DMA ----
    #pragma unroll
    for (int s = 0; s < 5; s++)
        if (s < nS)
            dma16(wslab + goff[s], &wls[0][0] + ((((s << 2) + wv) << 6) << 2));

    f4 acc0 = {0.f, 0.f, 0.f, 0.f};   // jg=0, 4 batches
    f4 acc1 = {0.f, 0.f, 0.f, 0.f};   // jg=1

    __syncthreads();   // x writes + chunk-0 DMA drained

    for (int ch = 0; ch < NCH; ch++) {
        const int cur = ch & 1;

        if (ch + 1 < NCH) {            // async prefetch, in flight across compute
            const float* gb = wslab + (ch + 1) * CHF;
            #pragma unroll
            for (int s = 0; s < 5; s++)
                if (s < nS)
                    dma16(gb + goff[s], &wls[cur ^ 1][0] + ((((s << 2) + wv) << 6) << 2));
        }

        #pragma unroll
        for (int cl = 0; cl < 4; cl++) {
            const int c = (ch << 2) + cl;

            // x fragments: wave-uniform broadcast b128 reads
            f4 xv[3][4];
            #pragma unroll
            for (int kh = 0; kh < 3; kh++)
                #pragma unroll
                for (int cc = 0; cc < 4; cc++)
                    xv[kh][cc] = *(const f4*)(&xls[c][kh][cc][wv << 2]);

            const int g0 = (cl * 9) >> 2;          // first granule of this cl
            #pragma unroll
            for (int jg = 0; jg < 2; jg++) {
                // lane-contiguous b128: float addr = pos*2304 + k4*256 + ln*4
                const float* base = &wls[cur][jg * 2304] + (ln << 2);
                const f4 ga = *(const f4*)(base + ((g0 + 0) << 8));
                const f4 gb = *(const f4*)(base + ((g0 + 1) << 8));
                const f4 gc = *(const f4*)(base + ((g0 + 2) << 8));
                float wk[9];
                if (cl == 0) {        // phase 0
                    wk[0]=ga.x; wk[1]=ga.y; wk[2]=ga.z; wk[3]=ga.w;
                    wk[4]=gb.x; wk[5]=gb.y; wk[6]=gb.z; wk[7]=gb.w; wk[8]=gc.x;
                } else if (cl == 1) { // phase 1
                    wk[0]=ga.y; wk[1]=ga.z; wk[2]=ga.w;
                    wk[3]=gb.x; wk[4]=gb.y; wk[5]=gb.z; wk[6]=gb.w;
                    wk[7]=gc.x; wk[8]=gc.y;
                } else if (cl == 2) { // phase 2
                    wk[0]=ga.z; wk[1]=ga.w;
                    wk[2]=gb.x; wk[3]=gb.y; wk[4]=gb.z; wk[5]=gb.w;
                    wk[6]=gc.x; wk[7]=gc.y; wk[8]=gc.z;
                } else {              // phase 3
                    wk[0]=ga.w;
                    wk[1]=gb.x; wk[2]=gb.y; wk[3]=gb.z; wk[4]=gb.w;
                    wk[5]=gc.x; wk[6]=gc.y; wk[7]=gc.z; wk[8]=gc.w;
                }
                #pragma unroll
                for (int kh = 0; kh < 3; kh++)
                    #pragma unroll
                    for (int kw = 0; kw < 3; kw++) {
                        const float w = wk[kh * 3 + kw];
                        if (jg == 0) acc0 += w * xv[kh][kw];
                        else         acc1 += w * xv[kh][kw + 1];
                    }
            }
        }

        if (ch + 1 < NCH)
            __syncthreads();   // drains our LDS reads + the prefetch DMA
    }

    // ---- epilogue: o = ln, f2 store over the 2 j's ----
    #pragma unroll
    for (int bb = 0; bb < 4; bb++) {
        const int b = (wv << 2) + bb;
        float* op = out + ((size_t)(b * COUT + ln) * HO + i) * WO + j0;
        const float v0 = (bb == 0) ? acc0.x : (bb == 1) ? acc0.y : (bb == 2) ? acc0.z : acc0.w;
        const float v1 = (bb == 0) ? acc1.x : (bb == 1) ? acc1.y : (bb == 2) ? acc1.z : acc1.w;
        f2 s; s.x = sigmoidf(v0); s.y = sigmoidf(v1);
        *(f2*)op = s;
    }
}

extern "C" void kernel_launch(void* const* d_in, const int* in_sizes, int n_in,
                              void* d_out, int out_size, void* d_ws, size_t ws_size,
                              hipStream_t stream) {
    const float* x   = (const float*)d_in[0];
    const float* wgt = (const float*)d_in[1];
    float* out       = (float*)d_out;
    const int grid = HO * (WO / JT);   // 62 * 31 = 1922
    lc2d_kernel<<<dim3(grid), dim3(256), 0, stream>>>(x, wgt, out);
}